// Round 4
// baseline (457.407 us; speedup 1.0000x reference)
//
#include <hip/hip_runtime.h>
#include <hip/hip_bf16.h>

#define B_ 128
#define T_ 300
#define TC_ 20
#define DW_ 16
#define DC_ 32
#define UC_ 32
#define UM_ 64
#define POS_ 20
#define PAR_ 8
#define VW_ 1834
#define VC_ 132
#define DIN_ 76
#define XS_ 80
#define NROW (B_*T_)

__device__ __forceinline__ float fast_sig(float x){
  return __builtin_amdgcn_rcpf(1.f + __expf(-x));
}
__device__ __forceinline__ float fast_tanh(float x){
  return __builtin_amdgcn_rcpf(1.f + __expf(-2.f*x))*2.f - 1.f;
}

// ---- prep: xzc[v][j] = sum_k emb_char[v][k]*char_Wx[k][j] + char_b[j]  (132 x 128)
__global__ void k_xzc(const float* __restrict__ emb_char, const float* __restrict__ Wx,
                      const float* __restrict__ bias, float* __restrict__ xzc){
  int v = blockIdx.x, j = threadIdx.x;
  float acc = bias[j];
  #pragma unroll
  for (int k=0;k<DC_;k++) acc += emb_char[v*DC_+k]*Wx[k*(4*UC_)+j];
  xzc[v*(4*UC_)+j] = acc;
}

// ---- fill x cols [0..16) = word emb, [48..68) = pos, [68..76) = par
__global__ void k_xfill(const int* __restrict__ word_in, const float* __restrict__ emb_wor,
                        const float* __restrict__ pos, const float* __restrict__ par,
                        float* __restrict__ x){
  int r = blockIdx.x*4 + threadIdx.x/80;
  int c = threadIdx.x%80;
  float v;
  if (c < DW_)                     v = emb_wor[word_in[r]*DW_ + c];
  else if (c < DW_+UC_)            return;             // char kernel fills
  else if (c < DW_+UC_+POS_)       v = pos[r*POS_ + (c-(DW_+UC_))];
  else if (c < DIN_)               v = par[r*PAR_ + (c-(DW_+UC_+POS_))];
  else                             return;             // pad, never read
  x[r*XS_ + c] = v;
}

// ---- char LSTM: thread = (seq, unit). 8 seqs/block, 32 threads/seq.
// wh[4][32] PINNED in VGPRs via asm; h exchanged via LDS within the 32-group
// (wave-synchronous, no barrier in step loop).
__global__ __launch_bounds__(256,1) void k_char(const int* __restrict__ char_in,
        const float* __restrict__ xzc, const float* __restrict__ Wh,
        float* __restrict__ x){
  __shared__ float hbuf[8][32];
  __shared__ int sidx[8*TC_];
  const int tid = threadIdx.x;
  const int u = tid & 31;               // unit
  const int grp = tid >> 5;             // 0..7 seq group in block
  const int seq = blockIdx.x*8 + grp;

  if (tid < 8*TC_) sidx[tid] = char_in[blockIdx.x*(8*TC_) + tid];
  hbuf[grp][u] = 0.f;

  // wh[g][k] = Wh[k*128 + g*32 + u] : coalesced across u; pinned so the
  // compiler cannot sink these loads into the recurrence loop.
  float wh[4][32];
  #pragma unroll
  for (int g=0; g<4; g++)
    #pragma unroll
    for (int k=0; k<32; k++)
      wh[g][k] = Wh[k*(4*UC_) + g*32 + u];
  #pragma unroll
  for (int g=0; g<4; g++)
    #pragma unroll
    for (int k=0; k<32; k++)
      asm volatile("" : "+v"(wh[g][k]));

  __syncthreads();

  float h = 0.f, c = 0.f;
  int idx = sidx[grp*TC_ + 0];
  float zx[4];
  #pragma unroll
  for (int g=0; g<4; g++) zx[g] = xzc[idx*(4*UC_) + g*32 + u];

  for (int t=0; t<TC_; t++){
    int idxn = (t+1 < TC_) ? sidx[grp*TC_ + t+1] : 0;
    float nzx[4];
    #pragma unroll
    for (int g=0; g<4; g++) nzx[g] = xzc[idxn*(4*UC_) + g*32 + u];  // prefetch

    float zi = zx[0], zf = zx[1], zg = zx[2], zo = zx[3];
    const float4* hb4 = reinterpret_cast<const float4*>(&hbuf[grp][0]);
    #pragma unroll
    for (int k4=0; k4<8; k4++){
      float4 hv = hb4[k4];
      float he[4] = {hv.x, hv.y, hv.z, hv.w};
      #pragma unroll
      for (int e=0; e<4; e++){
        int k = k4*4+e;
        zi += he[e]*wh[0][k]; zf += he[e]*wh[1][k];
        zg += he[e]*wh[2][k]; zo += he[e]*wh[3][k];
      }
    }
    float cn = fast_sig(zf)*c + fast_sig(zi)*fast_tanh(zg);
    float hn = fast_sig(zo)*fast_tanh(cn);
    bool m = (idx != 0);
    c = m ? cn : c;
    h = m ? hn : h;
    hbuf[grp][u] = h;                   // same-wave exchange, lgkmcnt-ordered
    idx = idxn;
    #pragma unroll
    for (int g=0; g<4; g++) zx[g] = nzx[g];
  }
  x[seq*XS_ + DW_ + u] = h;
}

// ---- xz GEMM: xz[row][j] = x_row · Wx[:,j] + b[j], j<256 fwd, j>=256 bwd. bf16 out.
__global__ __launch_bounds__(512,1) void k_xz(const float* __restrict__ x,
      const float* __restrict__ Wx_f, const float* __restrict__ b_f,
      const float* __restrict__ Wx_b, const float* __restrict__ b_b,
      __hip_bfloat16* __restrict__ xz){
  __shared__ float xs[16*XS_];
  const int j = threadIdx.x;
  const int jj = j & 255;
  const bool bwd = (j >= 256);
  const float* Wx = bwd ? Wx_b : Wx_f;
  const float bj = bwd ? b_b[jj] : b_f[jj];

  float w[DIN_];
  #pragma unroll
  for (int k=0; k<DIN_; k++) w[k] = Wx[k*(4*UM_) + jj];
  #pragma unroll
  for (int k=0; k<DIN_; k++) asm volatile("" : "+v"(w[k]));

  const int rowbase = blockIdx.x*16;
  for (int i=j; i<16*XS_; i+=512) xs[i] = x[rowbase*XS_ + i];
  __syncthreads();

  for (int r=0; r<16; r++){
    const float4* xr = reinterpret_cast<const float4*>(&xs[r*XS_]);
    float a0=bj, a1=0.f, a2=0.f, a3=0.f;
    #pragma unroll
    for (int c4=0; c4<19; c4++){
      float4 v = xr[c4];
      a0 += v.x*w[4*c4+0]; a1 += v.y*w[4*c4+1];
      a2 += v.z*w[4*c4+2]; a3 += v.w*w[4*c4+3];
    }
    xz[(size_t)(rowbase+r)*512 + j] = __float2bfloat16((a0+a1)+(a2+a3));
  }
}

// ---- word LSTM: one block per (batch, dir); thread j owns gate column j.
// Weights PINNED in VGPRs; raw s_barrier (no vmcnt drain) once per step;
// xz pointer-walked with 1-step register prefetch; word mask staged in LDS.
__global__ __launch_bounds__(256,1) void k_rnn(const __hip_bfloat16* __restrict__ xz,
      const int* __restrict__ word_in,
      const float* __restrict__ Wh_f, const float* __restrict__ Wh_b,
      float* __restrict__ hcat){
  __shared__ float zbuf[2][4*UM_];
  __shared__ float hbuf[4][UM_];
  __shared__ int wm[T_];
  const int j = threadIdx.x;
  const int w = j >> 6;
  const int l = j & 63;
  const int dir = blockIdx.x & 1;
  const int b = blockIdx.x >> 1;
  const float* Wh = dir ? Wh_b : Wh_f;

  float wh[UM_];
  #pragma unroll
  for (int k=0;k<UM_;k++) wh[k] = Wh[k*(4*UM_) + j];
  #pragma unroll
  for (int k=0;k<UM_;k++) asm volatile("" : "+v"(wh[k]));

  for (int t=j; t<T_; t+=256){
    int row = b*T_ + (dir ? (T_-1-t) : t);
    wm[t] = word_in[row];
  }
  hbuf[w][l] = 0.f;                     // per-wave copy
  __syncthreads();

  float h = 0.f, cc = 0.f;
  const size_t r0 = (size_t)(b*T_ + (dir ? T_-1 : 0));
  const __hip_bfloat16* xp = xz + r0*512 + dir*256 + j;
  const ptrdiff_t dstep = dir ? -512 : 512;
  float* hout = hcat + r0*(2*UM_) + dir*UM_ + l;
  const ptrdiff_t hstep = dir ? -(2*UM_) : (2*UM_);

  float zx = __bfloat162float(*xp);

  for (int t=0;t<T_;t++){
    float zxn = 0.f;
    if (t+1 < T_) zxn = __bfloat162float(xp[dstep]);   // prefetch next step

    float a0=0.f, a1=0.f, a2=0.f, a3=0.f;
    const float4* hb4 = reinterpret_cast<const float4*>(&hbuf[w][0]);
    #pragma unroll
    for (int k4=0;k4<16;k4++){
      float4 hv = hb4[k4];
      a0 += hv.x*wh[k4*4+0]; a1 += hv.y*wh[k4*4+1];
      a2 += hv.z*wh[k4*4+2]; a3 += hv.w*wh[k4*4+3];
    }
    zbuf[t&1][j] = zx + ((a0+a1)+(a2+a3));
    asm volatile("s_waitcnt lgkmcnt(0)" ::: "memory");
    __builtin_amdgcn_s_barrier();
    asm volatile("" ::: "memory");

    float zi = zbuf[t&1][l],     zf = zbuf[t&1][64+l];
    float zg = zbuf[t&1][128+l], zo = zbuf[t&1][192+l];
    int mw = wm[t];
    float cn = fast_sig(zf)*cc + fast_sig(zi)*fast_tanh(zg);
    float hn = fast_sig(zo)*fast_tanh(cn);
    if (mw != 0){ cc = cn; h = hn; }    // every wave updates all 64 units
    hbuf[w][l] = h;                     // within-wave, visible next step
    if (w == 0) *hout = h;              // fire-and-forget, never drained
    hout += hstep;
    zx = zxn; xp += dstep;
  }
}

// ---- dense + softmax
__global__ void k_dense(const float* __restrict__ hcat, const float* __restrict__ W,
                        const float* __restrict__ bias, float* __restrict__ out){
  int r = blockIdx.x*256 + threadIdx.x;
  const float4* h4 = reinterpret_cast<const float4*>(hcat + (size_t)r*(2*UM_));
  float a0=bias[0], a1=bias[1], a2=bias[2], a3=bias[3];
  #pragma unroll
  for (int k4=0;k4<32;k4++){
    float4 hv = h4[k4];
    float he[4] = {hv.x, hv.y, hv.z, hv.w};
    #pragma unroll
    for (int e=0;e<4;e++){
      int k = k4*4+e;
      a0 += he[e]*W[k*4+0]; a1 += he[e]*W[k*4+1];
      a2 += he[e]*W[k*4+2]; a3 += he[e]*W[k*4+3];
    }
  }
  float mx = fmaxf(fmaxf(a0,a1), fmaxf(a2,a3));
  float e0=__expf(a0-mx), e1=__expf(a1-mx), e2=__expf(a2-mx), e3=__expf(a3-mx);
  float s = __builtin_amdgcn_rcpf(e0+e1+e2+e3);
  out[r*4+0]=e0*s; out[r*4+1]=e1*s; out[r*4+2]=e2*s; out[r*4+3]=e3*s;
}

extern "C" void kernel_launch(void* const* d_in, const int* in_sizes, int n_in,
                              void* d_out, int out_size, void* d_ws, size_t ws_size,
                              hipStream_t stream) {
  const int*   word_in  = (const int*)  d_in[0];
  const int*   char_in  = (const int*)  d_in[1];
  const float* inp_pos  = (const float*)d_in[2];
  const float* inp_par  = (const float*)d_in[3];
  const float* emb_wor  = (const float*)d_in[4];
  const float* emb_char = (const float*)d_in[5];
  const float* char_Wx  = (const float*)d_in[6];
  const float* char_Wh  = (const float*)d_in[7];
  const float* char_b   = (const float*)d_in[8];
  const float* fwd_Wx   = (const float*)d_in[9];
  const float* fwd_Wh   = (const float*)d_in[10];
  const float* fwd_b    = (const float*)d_in[11];
  const float* bwd_Wx   = (const float*)d_in[12];
  const float* bwd_Wh   = (const float*)d_in[13];
  const float* bwd_b    = (const float*)d_in[14];
  const float* dense_W  = (const float*)d_in[15];
  const float* dense_b  = (const float*)d_in[16];
  float* out = (float*)d_out;

  float* xw   = (float*)d_ws;                      // NROW*XS_            f32
  float* hcat = xw + (size_t)NROW*XS_;             // NROW*128            f32
  float* xzc  = hcat + (size_t)NROW*128;           // 132*128             f32
  __hip_bfloat16* xzw = (__hip_bfloat16*)(xzc + (size_t)VC_*128);  // NROW*512 bf16

  k_xzc  <<<VC_, 4*UC_, 0, stream>>>(emb_char, char_Wx, char_b, xzc);
  k_xfill<<<NROW/4, 320, 0, stream>>>(word_in, emb_wor, inp_pos, inp_par, xw);
  k_char <<<NROW/8, 256, 0, stream>>>(char_in, xzc, char_Wh, xw);
  k_xz   <<<NROW/16, 512, 0, stream>>>(xw, fwd_Wx, fwd_b, bwd_Wx, bwd_b, xzw);
  k_rnn  <<<2*B_, 256, 0, stream>>>(xzw, word_in, fwd_Wh, bwd_Wh, hcat);
  k_dense<<<NROW/256, 256, 0, stream>>>(hcat, dense_W, dense_b, out);
}